// Round 4
// baseline (2111.674 us; speedup 1.0000x reference)
//
#include <hip/hip_runtime.h>
#include <math.h>

#define Ee   200
#define Hh   128
#define G4   512          // 4*H
#define Kk   24
#define Bb   64
#define Tt   1024
#define HIDd 256
#define NEGf (-10000.0f)

// ---------------------------------------------------------------------------
// K0: Wt[k][n] (k<200, n<1024): n<512 -> W_ih_f[n][k], else W_ih_b[n-512][k]
// ---------------------------------------------------------------------------
__global__ __launch_bounds__(256) void k_wt(const float* __restrict__ Wf,
                                            const float* __restrict__ Wb,
                                            float* __restrict__ Wt) {
    int idx = blockIdx.x * 256 + threadIdx.x;
    if (idx >= Ee * 1024) return;
    int k = idx >> 10, n = idx & 1023;
    Wt[idx] = (n < G4) ? Wf[n * Ee + k] : Wb[(n - G4) * Ee + k];
}

// ---------------------------------------------------------------------------
// K1: fused gather+GEMM, BM=128 BN=256 BK=8, register-prefetch double buffer.
// ---------------------------------------------------------------------------
__global__ __launch_bounds__(256, 2) void k_gemm2(const int* __restrict__ sent,
                                                  const float* __restrict__ emb,
                                                  const float* __restrict__ Wt,
                                                  float* __restrict__ Uc,
                                                  int c0T, int CT, int unified) {
    __shared__ float As[8][128];
    __shared__ float Bs[8][256];
    __shared__ int   toks[128];

    int tid = threadIdx.x;
    int n0  = blockIdx.x * 256;
    int m0  = blockIdx.y * 128;
    int dz  = blockIdx.z;
    int ty  = tid >> 4, tx = tid & 15;

    if (tid < 128) {
        int m = m0 + tid;
        int it = m >> 6, b = m & 63;
        int t = unified ? it : (dz ? (Tt - 1 - (c0T + it)) : (c0T + it));
        toks[tid] = sent[b * Tt + t];
    }
    __syncthreads();

    int am = tid & 127, ak4 = tid >> 7;       // A staging
    int brow = tid >> 5, bc4 = tid & 31;      // B staging

    const float* aptr = emb + (size_t)toks[am] * Ee + ak4 * 4;
    int bcol0 = (unified ? 0 : dz * G4) + n0;
    const float* bptr = Wt + (size_t)brow * 1024 + bcol0 + bc4 * 4;

    float acc[8][16];
#pragma unroll
    for (int i = 0; i < 8; ++i)
#pragma unroll
        for (int j = 0; j < 16; ++j) acc[i][j] = 0.f;

    // preload tile 0 into registers
    float4 av  = *(const float4*)(aptr);
    float4 bv0 = *(const float4*)(bptr);
    float4 bv1 = *(const float4*)(bptr + 128);

    for (int kc = 0; kc < Ee; kc += 8) {
        As[ak4 * 4 + 0][am] = av.x;
        As[ak4 * 4 + 1][am] = av.y;
        As[ak4 * 4 + 2][am] = av.z;
        As[ak4 * 4 + 3][am] = av.w;
        *(float4*)&Bs[brow][bc4 * 4]       = bv0;
        *(float4*)&Bs[brow][128 + bc4 * 4] = bv1;
        __syncthreads();

        if (kc + 8 < Ee) {                     // prefetch next tile (latency
            av  = *(const float4*)(aptr + kc + 8);              // hidden under
            bv0 = *(const float4*)(bptr + (size_t)(kc + 8) * 1024);   // compute)
            bv1 = *(const float4*)(bptr + (size_t)(kc + 8) * 1024 + 128);
        }

#pragma unroll
        for (int k = 0; k < 8; ++k) {
            float a_[8], b_[16];
            *(float4*)&a_[0] = *(const float4*)&As[k][ty * 8];
            *(float4*)&a_[4] = *(const float4*)&As[k][ty * 8 + 4];
#pragma unroll
            for (int q = 0; q < 4; ++q)
                *(float4*)&b_[4 * q] = *(const float4*)&Bs[k][tx * 4 + 64 * q];
#pragma unroll
            for (int i = 0; i < 8; ++i)
#pragma unroll
                for (int j = 0; j < 16; ++j)
                    acc[i][j] = fmaf(a_[i], b_[j], acc[i][j]);
        }
        __syncthreads();
    }

    int dd   = unified ? (n0 >> 9) : dz;
    int ncol = unified ? (n0 & 511) : n0;
    float* base = Uc + (size_t)dd * ((size_t)CT * Bb * G4);
#pragma unroll
    for (int i = 0; i < 8; ++i) {
        float* dst = base + (size_t)(m0 + ty * 8 + i) * G4 + ncol + tx * 4;
#pragma unroll
        for (int q = 0; q < 4; ++q)
            *(float4*)(dst + 64 * q) = make_float4(acc[i][4 * q], acc[i][4 * q + 1],
                                                   acc[i][4 * q + 2], acc[i][4 * q + 3]);
    }
}

// ---------------------------------------------------------------------------
// K2: LSTM recurrence, register-resident h, 2 barriers/step.
//   128 blocks = (dir,b), 512 thr (8 waves). Wave w owns h-cols [16w,16w+16).
//   P1: lane l computes partials for rows {64i+l} (its 16 cols) -> ps
//       + tag partials (lane<24) from hv regs.
//   P2: wave w reduces rows {gt*128+16w+co} (lane=gt*16+co), activates,
//       does the cell via 4 intra-wave shfls, re-broadcasts hv via 16 shfls.
//       Wave 7 lanes<24 additionally reduce+store tag row of h(i-1).
//   ps layout: gate row r -> r*9 + (r>>7)*2 + w   (pad kills 4-way conflict)
//              tag  row k -> (512+k)*9 + 8 + w
// ---------------------------------------------------------------------------
__global__ __launch_bounds__(512, 2) void k_lstm4(const float* __restrict__ Uc,
                                                  const float* __restrict__ Whh_f,
                                                  const float* __restrict__ Whh_b,
                                                  const float* __restrict__ bih_f,
                                                  const float* __restrict__ bhh_f,
                                                  const float* __restrict__ bih_b,
                                                  const float* __restrict__ bhh_b,
                                                  const float* __restrict__ h0v,
                                                  const float* __restrict__ c0v,
                                                  const float* __restrict__ Wout,
                                                  float* __restrict__ hst,
                                                  float* __restrict__ cst,
                                                  float* __restrict__ pf,
                                                  int c0T, int CT, int first, int unified) {
    __shared__ float ps[4840];

    int tid  = threadIdx.x;
    int lane = tid & 63, wv = tid >> 6;
    int b = blockIdx.x & 63, d = blockIdx.x >> 6;
    int gt = lane >> 4, co = lane & 15;

    const float* Whh = d ? Whh_b : Whh_f;

    // P1 weights: rows {64*ri+lane} x cols [16wv,16wv+16)
    float w[8][16];
#pragma unroll
    for (int ri = 0; ri < 8; ++ri) {
        const float* wr = Whh + (size_t)(ri * 64 + lane) * Hh + wv * 16;
#pragma unroll
        for (int c4 = 0; c4 < 4; ++c4)
            *(float4*)&w[ri][c4 * 4] = *(const float4*)(wr + c4 * 4);
    }
    // tag weights (lane<24), same 16 cols
    float wt[16];
    if (lane < Kk) {
        const float* wr = Wout + (size_t)lane * HIDd + d * Hh + wv * 16;
#pragma unroll
        for (int c4 = 0; c4 < 4; ++c4)
            *(float4*)&wt[c4 * 4] = *(const float4*)(wr + c4 * 4);
    }

    // P2 row owned by this lane
    int R = gt * Hh + wv * 16 + co;
    float bias = d ? (bih_b[R] + bhh_b[R]) : (bih_f[R] + bhh_f[R]);

    // state: c and h for col (16wv+lane) on lanes<16
    float cc = 0.f, hnew = 0.f;
    int s0 = (d * Bb + b) * Hh + wv * 16;
    if (lane < 16) {
        hnew = first ? h0v[s0 + lane] : hst[s0 + lane];
        cc   = first ? c0v[s0 + lane] : cst[s0 + lane];
    }
    float hv[16];
#pragma unroll
    for (int c = 0; c < 16; ++c) hv[c] = __shfl(hnew, c);

    const float* Ub = Uc + (size_t)d * ((size_t)CT * Bb * G4);
    int u0 = unified ? (d ? (Tt - 1) : 0) : 0;
    int us = unified ? (d ? -1 : 1) : 1;
    const float* up = Ub + ((size_t)u0 * Bb + b) * G4 + R;
    long ustep = (long)us * Bb * G4;
    float ucur = *up;

    for (int i = 0; i < CT; ++i) {
        // ---- P1: partial dots from register hv ----
#pragma unroll
        for (int ri = 0; ri < 8; ++ri) {
            float s = 0.f;
#pragma unroll
            for (int c = 0; c < 16; ++c) s = fmaf(w[ri][c], hv[c], s);
            ps[(ri * 64 + lane) * 9 + (ri >> 1) * 2 + wv] = s;
        }
        if (lane < Kk) {
            float s = 0.f;
#pragma unroll
            for (int c = 0; c < 16; ++c) s = fmaf(wt[c], hv[c], s);
            ps[(G4 + lane) * 9 + 8 + wv] = s;
        }
        __syncthreads();

        // ---- P2: reduce own row, activate, cell, re-broadcast ----
        float unext = (i + 1 < CT) ? up[ustep] : 0.f;

        const float* pr = ps + R * 9 + (gt << 1);
        float s = ((pr[0] + pr[1]) + (pr[2] + pr[3])) +
                  ((pr[4] + pr[5]) + (pr[6] + pr[7]));
        s += ucur + bias;
        float gv = (gt == 2) ? tanhf(s) : 1.f / (1.f + expf(-s));

        if (wv == 7 && lane < Kk && i > 0) {        // tag row of h(i-1)
            const float* tq = ps + (G4 + lane) * 9 + 8;
            float ts = ((tq[0] + tq[1]) + (tq[2] + tq[3])) +
                       ((tq[4] + tq[5]) + (tq[6] + tq[7]));
            int tp = c0T + i - 1;
            int tg = d ? (Tt - 1 - tp) : tp;
            pf[((size_t)(d * Bb + b) * Tt + tg) * Kk + lane] = ts;
        }

        float gi = __shfl(gv, co);
        float gf = __shfl(gv, 16 + co);
        float gg = __shfl(gv, 32 + co);
        float go = __shfl(gv, 48 + co);
        cc = gf * cc + gi * gg;                    // garbage on lanes>=16 (unused)
        hnew = go * tanhf(cc);
#pragma unroll
        for (int c = 0; c < 16; ++c) hv[c] = __shfl(hnew, c);

        ucur = unext;
        up += ustep;
        __syncthreads();
    }

    // epilogue: tag row of h(CT-1)
    if (lane < Kk) {
        float s = 0.f;
#pragma unroll
        for (int c = 0; c < 16; ++c) s = fmaf(wt[c], hv[c], s);
        ps[(G4 + lane) * 9 + 8 + wv] = s;
    }
    __syncthreads();
    if (wv == 7 && lane < Kk) {
        const float* tq = ps + (G4 + lane) * 9 + 8;
        float ts = ((tq[0] + tq[1]) + (tq[2] + tq[3])) +
                   ((tq[4] + tq[5]) + (tq[6] + tq[7]));
        int tp = c0T + CT - 1;
        int tg = d ? (Tt - 1 - tp) : tp;
        pf[((size_t)(d * Bb + b) * Tt + tg) * Kk + lane] = ts;
    }
    if (lane < 16) {
        hst[s0 + lane] = hnew;
        cst[s0 + lane] = cc;
    }
}

// ---------------------------------------------------------------------------
// K3: Viterbi. 1 wave per b; v in lane regs; feat prefetch one step ahead.
// ---------------------------------------------------------------------------
__global__ __launch_bounds__(64) void k_viterbi(const float* __restrict__ pf,
                                                const float* __restrict__ bout,
                                                const float* __restrict__ trans,
                                                float* __restrict__ out) {
    __shared__ unsigned char bptr[Tt * Kk];
    __shared__ float tsh[Kk];
    __shared__ unsigned char path[Tt];

    int lane = threadIdx.x;
    int b    = blockIdx.x;
    int half   = (lane >= Kk) ? 1 : 0;
    int n      = half ? (lane - Kk) : lane;
    int active = (lane < 2 * Kk);

    float tr[12];
    float bo = 0.f;
    if (active) {
#pragma unroll
        for (int j = 0; j < 12; ++j) tr[j] = trans[n * Kk + half * 12 + j];
        bo = bout[n];
    }
    float v = (active && half == 0 && n == 0) ? 0.f : NEGf;   // START=0

    const float* p0 = pf + (size_t)b * Tt * Kk;
    const float* p1 = pf + (size_t)(Bb + b) * Tt * Kk;

    float pre = (active && half == 0) ? (p0[n] + p1[n]) : 0.f;

    for (int t = 0; t < Tt; ++t) {
        float pren = 0.f;
        if (t + 1 < Tt && active && half == 0)
            pren = p0[(t + 1) * Kk + n] + p1[(t + 1) * Kk + n];

        float best = NEGf;
        int   bp   = 0;
        if (active) {
            int pb = half * 12;
            best = __shfl(v, pb) + tr[0];
            bp   = pb;
#pragma unroll
            for (int j = 1; j < 12; ++j) {
                float s = __shfl(v, pb + j) + tr[j];
                if (s > best) { best = s; bp = pb + j; }   // strict >: first-max
            }
        }
        float ob  = __shfl(best, n + Kk);
        int   obp = __shfl(bp,   n + Kk);
        if (active && half == 0) {
            if (ob > best) { best = ob; bp = obp; }        // tie -> lower half
            float feat = pre + bo;
            v = best + feat;
            bptr[t * Kk + n] = (unsigned char)bp;
        }
        pre = pren;
    }

    if (half == 0 && lane < Kk) tsh[n] = v + trans[1 * Kk + n];   // STOP=1
    __syncthreads();

    if (lane == 0) {
        float bestv = tsh[0];
        int tag = 0;
        for (int q = 1; q < Kk; ++q)
            if (tsh[q] > bestv) { bestv = tsh[q]; tag = q; }
        out[b] = bestv;
        for (int t = Tt - 1; t >= 1; --t) {
            path[t] = (unsigned char)tag;
            tag = bptr[t * Kk + tag];
        }
        path[0] = (unsigned char)tag;
    }
    __syncthreads();

    float* otag = out + Bb + (size_t)b * Tt;
    for (int t = lane; t < Tt; t += 64) otag[t] = (float)path[t];
}

// ---------------------------------------------------------------------------
// host launcher
// ---------------------------------------------------------------------------
extern "C" void kernel_launch(void* const* d_in, const int* in_sizes, int n_in,
                              void* d_out, int out_size, void* d_ws, size_t ws_size,
                              hipStream_t stream) {
    const int*   sent  = (const int*)d_in[0];
    const float* emb   = (const float*)d_in[2];
    const float* Wih_f = (const float*)d_in[3];
    const float* Whh_f = (const float*)d_in[4];
    const float* bih_f = (const float*)d_in[5];
    const float* bhh_f = (const float*)d_in[6];
    const float* Wih_b = (const float*)d_in[7];
    const float* Whh_b = (const float*)d_in[8];
    const float* bih_b = (const float*)d_in[9];
    const float* bhh_b = (const float*)d_in[10];
    const float* h0    = (const float*)d_in[11];
    const float* c0    = (const float*)d_in[12];
    const float* Wout  = (const float*)d_in[13];
    const float* bout  = (const float*)d_in[14];
    const float* trans = (const float*)d_in[15];

    float* ws  = (float*)d_ws;
    float* Wt  = ws;                       //   204,800 f
    float* pf  = Wt + 204800;              // 3,145,728 f
    float* hst = pf + 3145728;             //    16,384 f
    float* cst = hst + 16384;              //    16,384 f
    float* Uc  = cst + 16384;

    const size_t fixedf = 204800 + 3145728 + 16384 + 16384;
    size_t needU = (size_t)2 * Tt * Bb * G4;
    int unified = ((fixedf + needU) * 4 <= ws_size);

    k_wt<<<(Ee * 1024 + 255) / 256, 256, 0, stream>>>(Wih_f, Wih_b, Wt);

    if (unified) {
        k_gemm2<<<dim3(4, 512, 1), 256, 0, stream>>>(sent, emb, Wt, Uc, 0, Tt, 1);
        k_lstm4<<<128, 512, 0, stream>>>(Uc, Whh_f, Whh_b, bih_f, bhh_f,
                                         bih_b, bhh_b, h0, c0, Wout,
                                         hst, cst, pf, 0, Tt, 1, 1);
    } else {
        int CT = 64;
        const int cands[3] = {512, 256, 128};
        for (int ci = 0; ci < 3; ++ci)
            if ((fixedf + (size_t)2 * cands[ci] * Bb * G4) * 4 <= ws_size) {
                CT = cands[ci]; break;
            }
        int NC = Tt / CT;
        for (int cix = 0; cix < NC; ++cix) {
            k_gemm2<<<dim3(2, CT * 64 / 128, 2), 256, 0, stream>>>(
                sent, emb, Wt, Uc, cix * CT, CT, 0);
            k_lstm4<<<128, 512, 0, stream>>>(Uc, Whh_f, Whh_b, bih_f, bhh_f,
                                             bih_b, bhh_b, h0, c0, Wout,
                                             hst, cst, pf, cix * CT, CT, cix == 0, 0);
        }
    }

    k_viterbi<<<Bb, 64, 0, stream>>>(pf, bout, trans, (float*)d_out);
}